// Round 8
// baseline (228.365 us; speedup 1.0000x reference)
//
#include <hip/hip_runtime.h>
#include <math.h>

#define T_TOKENS 8192
#define NEXP 64
#define HID 2048
#define NITER 30
#define SINK_BLOCKS 16       // r7: halved participants (was 32)
#define SINK_THREADS 512     // r7: 8 waves, 512 tokens/block
#define WREG 131072          // bf16 elements per W region (64 x 2048)
#define FLPAD 32             // floats per flag slot (128 B, own cache line)

typedef __bf16 bf16_t;
typedef bf16_t bf16x8 __attribute__((ext_vector_type(8)));
typedef float  f32x4  __attribute__((ext_vector_type(4)));

__device__ __forceinline__ void gload_lds16(const void* g, void* l) {
    __builtin_amdgcn_global_load_lds(
        (const __attribute__((address_space(1))) unsigned int*)g,
        (__attribute__((address_space(3))) unsigned int*)l, 16, 0, 0);
}

// ---------------------------------------------------------------------------
// Kernel 0: W (64x2048 f32) -> hi/lo bf16, per-64k-chunk quad-XOR-swizzled,
// linear in the exact order gemm's global_load_lds consumes.
// ---------------------------------------------------------------------------
__global__ __launch_bounds__(256)
void prep_whl(const float* __restrict__ W, bf16_t* __restrict__ wsw)
{
    int gid = blockIdx.x * 256 + threadIdx.x;   // 0..32767
    int region = gid >> 14;                     // 0 = hi, 1 = lo
    int qid = gid & 16383;
    int c = qid >> 9, L = qid & 511;
    int r = L >> 3, slot = L & 7;
    int qi = slot ^ (r & 7);
    const float* src = W + (size_t)r * HID + c * 64 + qi * 8;
    float4 v0 = *(const float4*)src;
    float4 v1 = *(const float4*)(src + 4);
    float x[8] = {v0.x, v0.y, v0.z, v0.w, v1.x, v1.y, v1.z, v1.w};
    bf16x8 q;
#pragma unroll
    for (int i = 0; i < 8; i++) {
        bf16_t h = (bf16_t)x[i];
        q[i] = (region == 0) ? h : (bf16_t)(x[i] - (float)h);
    }
    *(bf16x8*)(wsw + (size_t)region * WREG + (size_t)qid * 8) = q;
}

// ---------------------------------------------------------------------------
// Kernel 1: split-K(2) MFMA GEMM — EXACT R2 version. Warm pass = 15 us (R4).
// ---------------------------------------------------------------------------
__global__ __launch_bounds__(256, 2)
void gemm_splitk(const float* __restrict__ A, const bf16_t* __restrict__ Wq,
                 float* __restrict__ part)
{
    __shared__ float  sA[3][32 * 64];       // 8 KB x3 (raw f32, swizzled chunks)
    __shared__ bf16_t sW[3][2][64 * 64];    // 8 KB x6 (hi/lo bf16, swizzled)

    const int tid = threadIdx.x, lane = tid & 63, wv = tid >> 6;
    const int ks   = blockIdx.x & 1;
    const int tok0 = (blockIdx.x >> 1) * 32;
    const int mgrp = wv >> 1, ngrp = wv & 1;
    const int g = lane >> 4, m = lane & 15;
    const int arow = mgrp * 16 + m;
    const int m7 = m & 7;

    f32x4 acc0 = {0.f, 0.f, 0.f, 0.f}, acc1 = {0.f, 0.f, 0.f, 0.f};

    // staging maps (2 A-instrs + 4 W-instrs per wave per chunk)
    int ap[2], acs[2];   // A: lds position block, swizzled source chunk
#pragma unroll
    for (int j = 0; j < 2; j++) {
        int p = (wv * 2 + j) * 64 + lane;          // 16B-position 0..511
        ap[j] = p;
        int r = p >> 4, slot = p & 15;
        acs[j] = slot ^ (r & 7);                   // source 16B-chunk within row
    }

#define STAGE_CHUNK(cc, dst)                                                    \
    {                                                                           \
        const int _cc = (cc);                                                   \
        const int _d  = (dst);                                                  \
        _Pragma("unroll")                                                       \
        for (int j = 0; j < 2; j++) {                                           \
            int r = ap[j] >> 4;                                                 \
            const float* src = A + (size_t)(tok0 + r) * HID + ks * 1024         \
                             + _cc * 64 + acs[j] * 4;                           \
            gload_lds16(src, &sA[_d][(wv * 2 + j) * 256]);                      \
        }                                                                       \
        const size_t chb = ((size_t)(ks * 16 + _cc) * 512) * 8;                 \
        _Pragma("unroll")                                                       \
        for (int j = 0; j < 2; j++) {                                           \
            size_t q8 = chb + (size_t)((wv * 2 + j) * 64 + lane) * 8;           \
            gload_lds16(Wq + q8,        &sW[_d][0][(wv * 2 + j) * 512]);        \
            gload_lds16(Wq + WREG + q8, &sW[_d][1][(wv * 2 + j) * 512]);        \
        }                                                                       \
    }

#define COMPUTE_CHUNK(bufi)                                                     \
    {                                                                           \
        const float*  sAc = sA[bufi];                                           \
        const bf16_t* sWh = sW[bufi][0];                                        \
        const bf16_t* sWl = sW[bufi][1];                                        \
        _Pragma("unroll")                                                       \
        for (int k32 = 0; k32 < 2; ++k32) {                                     \
            int s0 = (k32 * 8 + g * 2) ^ m7;                                    \
            float4 x0 = *(const float4*)&sAc[arow * 64 + s0 * 4];               \
            float4 x1 = *(const float4*)&sAc[arow * 64 + (s0 ^ 1) * 4];         \
            float xs[8] = {x0.x, x0.y, x0.z, x0.w, x1.x, x1.y, x1.z, x1.w};     \
            bf16x8 fAh, fAl;                                                    \
            _Pragma("unroll")                                                   \
            for (int i = 0; i < 8; i++) {                                       \
                bf16_t h = (bf16_t)xs[i];                                       \
                fAh[i] = h; fAl[i] = (bf16_t)(xs[i] - (float)h);                \
            }                                                                   \
            const int q = k32 * 4 + g;                                          \
            {                                                                   \
                int off = (ngrp * 32 + m) * 64 + (q ^ m7) * 8;                  \
                bf16x8 fWh = *(const bf16x8*)&sWh[off];                         \
                bf16x8 fWl = *(const bf16x8*)&sWl[off];                         \
                acc0 = __builtin_amdgcn_mfma_f32_16x16x32_bf16(fAh, fWh, acc0, 0, 0, 0); \
                acc0 = __builtin_amdgcn_mfma_f32_16x16x32_bf16(fAh, fWl, acc0, 0, 0, 0); \
                acc0 = __builtin_amdgcn_mfma_f32_16x16x32_bf16(fAl, fWh, acc0, 0, 0, 0); \
            }                                                                   \
            {                                                                   \
                int off = (ngrp * 32 + 16 + m) * 64 + (q ^ m7) * 8;             \
                bf16x8 fWh = *(const bf16x8*)&sWh[off];                         \
                bf16x8 fWl = *(const bf16x8*)&sWl[off];                         \
                acc1 = __builtin_amdgcn_mfma_f32_16x16x32_bf16(fAh, fWh, acc1, 0, 0, 0); \
                acc1 = __builtin_amdgcn_mfma_f32_16x16x32_bf16(fAh, fWl, acc1, 0, 0, 0); \
                acc1 = __builtin_amdgcn_mfma_f32_16x16x32_bf16(fAl, fWh, acc1, 0, 0, 0); \
            }                                                                   \
        }                                                                       \
    }

    // prologue: fill pipeline 2 deep (12 loads in flight per wave)
    STAGE_CHUNK(0, 0);
    STAGE_CHUNK(1, 1);

    for (int cc = 0; cc < 14; ++cc) {
        STAGE_CHUNK(cc + 2, (cc + 2) % 3);
        asm volatile("s_waitcnt vmcnt(12)" ::: "memory");
        asm volatile("s_barrier" ::: "memory");
        COMPUTE_CHUNK(cc % 3);
        asm volatile("s_barrier" ::: "memory");
    }
    asm volatile("s_waitcnt vmcnt(6)" ::: "memory");
    asm volatile("s_barrier" ::: "memory");
    COMPUTE_CHUNK(2);                      // chunk 14 -> buffer 14%3=2
    asm volatile("s_waitcnt vmcnt(0)" ::: "memory");
    asm volatile("s_barrier" ::: "memory");
    COMPUTE_CHUNK(0);                      // chunk 15 -> buffer 15%3=0

    float* pb = part + (size_t)ks * T_TOKENS * 64;
#pragma unroll
    for (int i = 0; i < 4; i++) {
        int t = tok0 + mgrp * 16 + g * 4 + i;     // C: row=(lane>>4)*4+reg
        pb[(size_t)t * 64 + ngrp * 32 + m]      = acc0[i];   // col=lane&15
        pb[(size_t)t * 64 + ngrp * 32 + 16 + m] = acc1[i];
    }
#undef STAGE_CHUNK
#undef COMPUTE_CHUNK
}

// ---------------------------------------------------------------------------
// Kernel 2: persistent sinkhorn. r7/r8: 16 blocks x 512 thr (8 waves), 512
// tokens/block. Sync chain STRUCTURE identical to proven R2 flag scheme
// (publish -> release fence -> padded flag -> paced poll -> gather); only
// the participant count halves: 16 flags polled, 16-value gather, half the
// publish/poll contention at the coherence point. Data-as-flag (R3/R6) is
// CLOSED (both hit the same 5.3 us/iter wall). LDS 141.5 KB (<160 KB/CU),
// 1 block/CU; >64 KB static LDS already proven at 71 KB (R2). All remote
// waits guard-bounded. R8 = byte-identical resubmission of R7 (container
// infra failure, no data; hypothesis still untested).
// ---------------------------------------------------------------------------
__global__ __launch_bounds__(SINK_THREADS, 1)
void sinkhorn_v7(const float* __restrict__ part,
                 float* __restrict__ out,
                 float* __restrict__ sd,      // 30*16*64 partial slots
                 float* __restrict__ fl)      // 30*16 flags, FLPAD-padded
{
    __shared__ float tile[8][64 * 68];       // 139.3 KB
    __shared__ float d1_lds[64];
    __shared__ float pl[8][64];
    const int tid = threadIdx.x, bid = blockIdx.x;
    const int wave = tid >> 6, lane = tid & 63;
    const int t = bid * SINK_THREADS + tid;

    float* logits = out;
    float* aff    = out + (size_t)T_TOKENS * 64;
    float* idx    = out + (size_t)2 * T_TOKENS * 64;

    const float* p0 = part + (size_t)t * 64;
    const float* p1 = part + (size_t)T_TOKENS * 64 + (size_t)t * 64;

    float c[64];
#pragma unroll
    for (int e4 = 0; e4 < 16; e4++) {
        float4 a = *(const float4*)(p0 + e4 * 4);
        float4 b = *(const float4*)(p1 + e4 * 4);
        float4 v = {a.x + b.x, a.y + b.y, a.z + b.z, a.w + b.w};
        *(float4*)(logits + (size_t)t * 64 + e4 * 4) = v;
        float4 sg;
        sg.x = (v.x >= 0.f) ? 1.f / (1.f + expf(-v.x)) : expf(v.x) / (1.f + expf(v.x));
        sg.y = (v.y >= 0.f) ? 1.f / (1.f + expf(-v.y)) : expf(v.y) / (1.f + expf(v.y));
        sg.z = (v.z >= 0.f) ? 1.f / (1.f + expf(-v.z)) : expf(v.z) / (1.f + expf(v.z));
        sg.w = (v.w >= 0.f) ? 1.f / (1.f + expf(-v.w)) : expf(v.w) / (1.f + expf(v.w));
        *(float4*)(aff + (size_t)t * 64 + e4 * 4) = sg;
        c[e4 * 4 + 0] = expf(v.x);
        c[e4 * 4 + 1] = expf(v.y);
        c[e4 * 4 + 2] = expf(v.z);
        c[e4 * 4 + 3] = expf(v.w);
    }
    if (tid < 64) d1_lds[tid] = 1.0f;
    __syncthreads();

    float d0 = 0.f;
    float* tw = tile[wave];

    for (int iter = 0; iter < NITER; ++iter) {
        // phase 1: d0[t] = (1/T) / (sum_e d1[e]*c[e] + eps)
        float s = 0.f;
#pragma unroll
        for (int e4 = 0; e4 < 16; e4++) {
            float4 dv = *(const float4*)(&d1_lds[e4 * 4]);
            s = fmaf(c[e4 * 4 + 0], dv.x, s);
            s = fmaf(c[e4 * 4 + 1], dv.y, s);
            s = fmaf(c[e4 * 4 + 2], dv.z, s);
            s = fmaf(c[e4 * 4 + 3], dv.w, s);
        }
        d0 = (1.0f / 8192.0f) / (s + 1e-8f);

        // phase 2: block-local column sums via per-wave LDS transpose
#pragma unroll
        for (int e4 = 0; e4 < 16; e4++) {
            float4 v;
            v.x = c[e4 * 4 + 0] * d0; v.y = c[e4 * 4 + 1] * d0;
            v.z = c[e4 * 4 + 2] * d0; v.w = c[e4 * 4 + 3] * d0;
            *(float4*)(&tw[lane * 68 + e4 * 4]) = v;
        }
        __syncthreads();
        float colsum = 0.f;
#pragma unroll 16
        for (int j = 0; j < 64; j++) colsum += tw[j * 68 + lane];
        pl[wave][lane] = colsum;
        __syncthreads();

        // cross-block: publish partial + flag; poll flags; gather once
        if (tid < 64) {
            float S = ((pl[0][tid] + pl[1][tid]) + (pl[2][tid] + pl[3][tid]))
                    + ((pl[4][tid] + pl[5][tid]) + (pl[6][tid] + pl[7][tid]));
            __hip_atomic_store(&sd[(size_t)(iter * SINK_BLOCKS + bid) * 64 + tid], S,
                               __ATOMIC_RELAXED, __HIP_MEMORY_SCOPE_AGENT);
            if (tid == 0) {
                __builtin_amdgcn_fence(__ATOMIC_RELEASE, "agent");
                __hip_atomic_store(&fl[(size_t)(iter * SINK_BLOCKS + bid) * FLPAD], 1.0f,
                                   __ATOMIC_RELAXED, __HIP_MEMORY_SCOPE_AGENT);
            }
            if (tid < SINK_BLOCKS) {
                int guard = 0;
                for (;;) {
                    float f = __hip_atomic_load(&fl[(size_t)(iter * SINK_BLOCKS + tid) * FLPAD],
                                                __ATOMIC_RELAXED, __HIP_MEMORY_SCOPE_AGENT);
                    if (f > 0.f || ++guard >= (1 << 20)) break;
                    __builtin_amdgcn_s_sleep(1);
                }
            }
            const float* base = sd + (size_t)iter * SINK_BLOCKS * 64 + tid;
            float v[SINK_BLOCKS];
#pragma unroll
            for (int b = 0; b < SINK_BLOCKS; b++)
                v[b] = __hip_atomic_load(base + b * 64, __ATOMIC_RELAXED,
                                         __HIP_MEMORY_SCOPE_AGENT);
            float S2 = 0.f;
#pragma unroll
            for (int b = 0; b < SINK_BLOCKS; b++) S2 += v[b];
            d1_lds[tid] = (1.0f / 64.0f) / (S2 + 1e-8f);
        }
        __syncthreads();
    }

    // argmax_e of d1[e]*c[e]*d0 (first max wins, like jnp.argmax)
    float best = -1.0f; int bi = 0;
#pragma unroll
    for (int e4 = 0; e4 < 16; e4++) {
        float4 dv = *(const float4*)(&d1_lds[e4 * 4]);
        float vv0 = (dv.x * c[e4 * 4 + 0]) * d0;
        float vv1 = (dv.y * c[e4 * 4 + 1]) * d0;
        float vv2 = (dv.z * c[e4 * 4 + 2]) * d0;
        float vv3 = (dv.w * c[e4 * 4 + 3]) * d0;
        if (vv0 > best) { best = vv0; bi = e4 * 4 + 0; }
        if (vv1 > best) { best = vv1; bi = e4 * 4 + 1; }
        if (vv2 > best) { best = vv2; bi = e4 * 4 + 2; }
        if (vv3 > best) { best = vv3; bi = e4 * 4 + 3; }
    }
    idx[t] = (float)bi;
}

extern "C" void kernel_launch(void* const* d_in, const int* in_sizes, int n_in,
                              void* d_out, int out_size, void* d_ws, size_t ws_size,
                              hipStream_t stream)
{
    (void)in_sizes; (void)n_in; (void)out_size; (void)ws_size;
    const float* hs = (const float*)d_in[0];   // 8192 x 2048 f32
    const float* W  = (const float*)d_in[1];   // 64 x 2048 f32
    float* out      = (float*)d_out;           // [logits | affinities | idx]

    bf16_t* wsw = (bf16_t*)d_ws;               // 512 KB prepped W (hi|lo)
    float*  part = (float*)d_ws + 131072;      // 4 MB: part[2][8192][64]
    float*  sd   = part + 2 * T_TOKENS * 64;   // sink partial slots
    float*  fl   = sd + NITER * SINK_BLOCKS * 64;  // padded flags

    prep_whl<<<128, 256, 0, stream>>>(W, wsw);
    gemm_splitk<<<512, 256, 0, stream>>>(hs, wsw, part);
    sinkhorn_v7<<<SINK_BLOCKS, SINK_THREADS, 0, stream>>>(part, out, sd, fl);
}

// Round 9
// 216.129 us; speedup vs baseline: 1.0566x; 1.0566x over previous
//
#include <hip/hip_runtime.h>
#include <math.h>

#define T_TOKENS 8192
#define NEXP 64
#define HID 2048
#define NITER 30
#define SINK_BLOCKS 64       // r9: doubled active CUs for the I/O phase
#define SINK_THREADS 128     // 2 waves, 128 tokens/block
#define WREG 131072          // bf16 elements per W region (64 x 2048)
#define FLPAD 32             // floats per flag slot (128 B, own cache line)

typedef __bf16 bf16_t;
typedef bf16_t bf16x8 __attribute__((ext_vector_type(8)));
typedef float  f32x4  __attribute__((ext_vector_type(4)));

__device__ __forceinline__ void gload_lds16(const void* g, void* l) {
    __builtin_amdgcn_global_load_lds(
        (const __attribute__((address_space(1))) unsigned int*)g,
        (__attribute__((address_space(3))) unsigned int*)l, 16, 0, 0);
}

// ---------------------------------------------------------------------------
// Kernel 0: W (64x2048 f32) -> hi/lo bf16, per-64k-chunk quad-XOR-swizzled,
// linear in the exact order gemm's global_load_lds consumes.
// ---------------------------------------------------------------------------
__global__ __launch_bounds__(256)
void prep_whl(const float* __restrict__ W, bf16_t* __restrict__ wsw)
{
    int gid = blockIdx.x * 256 + threadIdx.x;   // 0..32767
    int region = gid >> 14;                     // 0 = hi, 1 = lo
    int qid = gid & 16383;
    int c = qid >> 9, L = qid & 511;
    int r = L >> 3, slot = L & 7;
    int qi = slot ^ (r & 7);
    const float* src = W + (size_t)r * HID + c * 64 + qi * 8;
    float4 v0 = *(const float4*)src;
    float4 v1 = *(const float4*)(src + 4);
    float x[8] = {v0.x, v0.y, v0.z, v0.w, v1.x, v1.y, v1.z, v1.w};
    bf16x8 q;
#pragma unroll
    for (int i = 0; i < 8; i++) {
        bf16_t h = (bf16_t)x[i];
        q[i] = (region == 0) ? h : (bf16_t)(x[i] - (float)h);
    }
    *(bf16x8*)(wsw + (size_t)region * WREG + (size_t)qid * 8) = q;
}

// ---------------------------------------------------------------------------
// Kernel 1: split-K(2) MFMA GEMM — EXACT R2 version. Warm pass = 15 us (R4).
// r9: `part` now points at the OUT buffer (ks0 -> logits region, ks1 -> aff
// region); sinkhorn reads and overwrites in place (token-exclusive).
// ---------------------------------------------------------------------------
__global__ __launch_bounds__(256, 2)
void gemm_splitk(const float* __restrict__ A, const bf16_t* __restrict__ Wq,
                 float* __restrict__ part)
{
    __shared__ float  sA[3][32 * 64];       // 8 KB x3 (raw f32, swizzled chunks)
    __shared__ bf16_t sW[3][2][64 * 64];    // 8 KB x6 (hi/lo bf16, swizzled)

    const int tid = threadIdx.x, lane = tid & 63, wv = tid >> 6;
    const int ks   = blockIdx.x & 1;
    const int tok0 = (blockIdx.x >> 1) * 32;
    const int mgrp = wv >> 1, ngrp = wv & 1;
    const int g = lane >> 4, m = lane & 15;
    const int arow = mgrp * 16 + m;
    const int m7 = m & 7;

    f32x4 acc0 = {0.f, 0.f, 0.f, 0.f}, acc1 = {0.f, 0.f, 0.f, 0.f};

    // staging maps (2 A-instrs + 4 W-instrs per wave per chunk)
    int ap[2], acs[2];   // A: lds position block, swizzled source chunk
#pragma unroll
    for (int j = 0; j < 2; j++) {
        int p = (wv * 2 + j) * 64 + lane;          // 16B-position 0..511
        ap[j] = p;
        int r = p >> 4, slot = p & 15;
        acs[j] = slot ^ (r & 7);                   // source 16B-chunk within row
    }

#define STAGE_CHUNK(cc, dst)                                                    \
    {                                                                           \
        const int _cc = (cc);                                                   \
        const int _d  = (dst);                                                  \
        _Pragma("unroll")                                                       \
        for (int j = 0; j < 2; j++) {                                           \
            int r = ap[j] >> 4;                                                 \
            const float* src = A + (size_t)(tok0 + r) * HID + ks * 1024         \
                             + _cc * 64 + acs[j] * 4;                           \
            gload_lds16(src, &sA[_d][(wv * 2 + j) * 256]);                      \
        }                                                                       \
        const size_t chb = ((size_t)(ks * 16 + _cc) * 512) * 8;                 \
        _Pragma("unroll")                                                       \
        for (int j = 0; j < 2; j++) {                                           \
            size_t q8 = chb + (size_t)((wv * 2 + j) * 64 + lane) * 8;           \
            gload_lds16(Wq + q8,        &sW[_d][0][(wv * 2 + j) * 512]);        \
            gload_lds16(Wq + WREG + q8, &sW[_d][1][(wv * 2 + j) * 512]);        \
        }                                                                       \
    }

#define COMPUTE_CHUNK(bufi)                                                     \
    {                                                                           \
        const float*  sAc = sA[bufi];                                           \
        const bf16_t* sWh = sW[bufi][0];                                        \
        const bf16_t* sWl = sW[bufi][1];                                        \
        _Pragma("unroll")                                                       \
        for (int k32 = 0; k32 < 2; ++k32) {                                     \
            int s0 = (k32 * 8 + g * 2) ^ m7;                                    \
            float4 x0 = *(const float4*)&sAc[arow * 64 + s0 * 4];               \
            float4 x1 = *(const float4*)&sAc[arow * 64 + (s0 ^ 1) * 4];         \
            float xs[8] = {x0.x, x0.y, x0.z, x0.w, x1.x, x1.y, x1.z, x1.w};     \
            bf16x8 fAh, fAl;                                                    \
            _Pragma("unroll")                                                   \
            for (int i = 0; i < 8; i++) {                                       \
                bf16_t h = (bf16_t)xs[i];                                       \
                fAh[i] = h; fAl[i] = (bf16_t)(xs[i] - (float)h);                \
            }                                                                   \
            const int q = k32 * 4 + g;                                          \
            {                                                                   \
                int off = (ngrp * 32 + m) * 64 + (q ^ m7) * 8;                  \
                bf16x8 fWh = *(const bf16x8*)&sWh[off];                         \
                bf16x8 fWl = *(const bf16x8*)&sWl[off];                         \
                acc0 = __builtin_amdgcn_mfma_f32_16x16x32_bf16(fAh, fWh, acc0, 0, 0, 0); \
                acc0 = __builtin_amdgcn_mfma_f32_16x16x32_bf16(fAh, fWl, acc0, 0, 0, 0); \
                acc0 = __builtin_amdgcn_mfma_f32_16x16x32_bf16(fAl, fWh, acc0, 0, 0, 0); \
            }                                                                   \
            {                                                                   \
                int off = (ngrp * 32 + 16 + m) * 64 + (q ^ m7) * 8;             \
                bf16x8 fWh = *(const bf16x8*)&sWh[off];                         \
                bf16x8 fWl = *(const bf16x8*)&sWl[off];                         \
                acc1 = __builtin_amdgcn_mfma_f32_16x16x32_bf16(fAh, fWh, acc1, 0, 0, 0); \
                acc1 = __builtin_amdgcn_mfma_f32_16x16x32_bf16(fAh, fWl, acc1, 0, 0, 0); \
                acc1 = __builtin_amdgcn_mfma_f32_16x16x32_bf16(fAl, fWh, acc1, 0, 0, 0); \
            }                                                                   \
        }                                                                       \
    }

    // prologue: fill pipeline 2 deep (12 loads in flight per wave)
    STAGE_CHUNK(0, 0);
    STAGE_CHUNK(1, 1);

    for (int cc = 0; cc < 14; ++cc) {
        STAGE_CHUNK(cc + 2, (cc + 2) % 3);
        asm volatile("s_waitcnt vmcnt(12)" ::: "memory");
        asm volatile("s_barrier" ::: "memory");
        COMPUTE_CHUNK(cc % 3);
        asm volatile("s_barrier" ::: "memory");
    }
    asm volatile("s_waitcnt vmcnt(6)" ::: "memory");
    asm volatile("s_barrier" ::: "memory");
    COMPUTE_CHUNK(2);                      // chunk 14 -> buffer 14%3=2
    asm volatile("s_waitcnt vmcnt(0)" ::: "memory");
    asm volatile("s_barrier" ::: "memory");
    COMPUTE_CHUNK(0);                      // chunk 15 -> buffer 15%3=0

    float* pb = part + (size_t)ks * T_TOKENS * 64;
#pragma unroll
    for (int i = 0; i < 4; i++) {
        int t = tok0 + mgrp * 16 + g * 4 + i;     // C: row=(lane>>4)*4+reg
        pb[(size_t)t * 64 + ngrp * 32 + m]      = acc0[i];   // col=lane&15
        pb[(size_t)t * 64 + ngrp * 32 + 16 + m] = acc1[i];
    }
#undef STAGE_CHUNK
#undef COMPUTE_CHUNK
}

// ---------------------------------------------------------------------------
// Kernel 2: persistent sinkhorn. r9: 64 blocks x 128 thr (2 waves), 128
// tokens/block. Evidence (R2 vs R8): sync chain latency is participant-
// invariant (~3.1 us/iter at 16 AND 32 blocks); the I/O phase scales with
// active CUs (16 CUs cost +15 us vs 32). So double CUs: I/O ~15 -> ~8 us.
// Reads split-K halves IN PLACE from out (logits/aff regions, written by
// gemm), overwrites with final logits/aff (token-exclusive, race-free).
// Sync = proven R2 flag scheme (publish -> release fence -> padded flag ->
// poll -> gather), now 64 flags / 64-value gather.
// ---------------------------------------------------------------------------
__global__ __launch_bounds__(SINK_THREADS, 1)
void sinkhorn_v8(float* __restrict__ out,
                 float* __restrict__ sd,      // 30*64*64 partial slots
                 float* __restrict__ fl)      // 30*64 flags, FLPAD-padded
{
    __shared__ float tile[2][64 * 68];       // 34.8 KB
    __shared__ float d1_lds[64];
    __shared__ float pl[2][64];
    const int tid = threadIdx.x, bid = blockIdx.x;
    const int wave = tid >> 6, lane = tid & 63;
    const int t = bid * SINK_THREADS + tid;

    float* logits = out;
    float* aff    = out + (size_t)T_TOKENS * 64;
    float* idx    = out + (size_t)2 * T_TOKENS * 64;

    float* p0 = logits + (size_t)t * 64;     // ks=0 half (gemm wrote here)
    float* p1 = aff    + (size_t)t * 64;     // ks=1 half

    float c[64];
#pragma unroll
    for (int e4 = 0; e4 < 16; e4++) {
        float4 a = *(const float4*)(p0 + e4 * 4);
        float4 b = *(const float4*)(p1 + e4 * 4);
        float4 v = {a.x + b.x, a.y + b.y, a.z + b.z, a.w + b.w};
        *(float4*)(p0 + e4 * 4) = v;                 // final logits, in place
        float4 sg;
        sg.x = (v.x >= 0.f) ? 1.f / (1.f + expf(-v.x)) : expf(v.x) / (1.f + expf(v.x));
        sg.y = (v.y >= 0.f) ? 1.f / (1.f + expf(-v.y)) : expf(v.y) / (1.f + expf(v.y));
        sg.z = (v.z >= 0.f) ? 1.f / (1.f + expf(-v.z)) : expf(v.z) / (1.f + expf(v.z));
        sg.w = (v.w >= 0.f) ? 1.f / (1.f + expf(-v.w)) : expf(v.w) / (1.f + expf(v.w));
        *(float4*)(p1 + e4 * 4) = sg;                // final affinities, in place
        c[e4 * 4 + 0] = expf(v.x);
        c[e4 * 4 + 1] = expf(v.y);
        c[e4 * 4 + 2] = expf(v.z);
        c[e4 * 4 + 3] = expf(v.w);
    }
    if (tid < 64) d1_lds[tid] = 1.0f;
    __syncthreads();

    float d0 = 0.f;
    float* tw = tile[wave];

    for (int iter = 0; iter < NITER; ++iter) {
        // phase 1: d0[t] = (1/T) / (sum_e d1[e]*c[e] + eps)
        float s = 0.f;
#pragma unroll
        for (int e4 = 0; e4 < 16; e4++) {
            float4 dv = *(const float4*)(&d1_lds[e4 * 4]);
            s = fmaf(c[e4 * 4 + 0], dv.x, s);
            s = fmaf(c[e4 * 4 + 1], dv.y, s);
            s = fmaf(c[e4 * 4 + 2], dv.z, s);
            s = fmaf(c[e4 * 4 + 3], dv.w, s);
        }
        d0 = (1.0f / 8192.0f) / (s + 1e-8f);

        // phase 2: block-local column sums via per-wave LDS transpose
#pragma unroll
        for (int e4 = 0; e4 < 16; e4++) {
            float4 v;
            v.x = c[e4 * 4 + 0] * d0; v.y = c[e4 * 4 + 1] * d0;
            v.z = c[e4 * 4 + 2] * d0; v.w = c[e4 * 4 + 3] * d0;
            *(float4*)(&tw[lane * 68 + e4 * 4]) = v;
        }
        __syncthreads();
        float colsum = 0.f;
#pragma unroll 16
        for (int j = 0; j < 64; j++) colsum += tw[j * 68 + lane];
        pl[wave][lane] = colsum;
        __syncthreads();

        // cross-block: publish partial + flag; poll flags; gather once
        if (tid < 64) {
            float S = pl[0][tid] + pl[1][tid];
            __hip_atomic_store(&sd[(size_t)(iter * SINK_BLOCKS + bid) * 64 + tid], S,
                               __ATOMIC_RELAXED, __HIP_MEMORY_SCOPE_AGENT);
            if (tid == 0) {
                __builtin_amdgcn_fence(__ATOMIC_RELEASE, "agent");
                __hip_atomic_store(&fl[(size_t)(iter * SINK_BLOCKS + bid) * FLPAD], 1.0f,
                                   __ATOMIC_RELAXED, __HIP_MEMORY_SCOPE_AGENT);
            }
            {   // 64 lanes poll 64 flags, one each
                int guard = 0;
                for (;;) {
                    float f = __hip_atomic_load(&fl[(size_t)(iter * SINK_BLOCKS + tid) * FLPAD],
                                                __ATOMIC_RELAXED, __HIP_MEMORY_SCOPE_AGENT);
                    if (f > 0.f || ++guard >= (1 << 20)) break;
                    __builtin_amdgcn_s_sleep(1);
                }
            }
            const float* base = sd + (size_t)iter * SINK_BLOCKS * 64 + tid;
            float v[SINK_BLOCKS];
#pragma unroll
            for (int b = 0; b < SINK_BLOCKS; b++)
                v[b] = __hip_atomic_load(base + b * 64, __ATOMIC_RELAXED,
                                         __HIP_MEMORY_SCOPE_AGENT);
            float S2 = 0.f;
#pragma unroll
            for (int b = 0; b < SINK_BLOCKS; b++) S2 += v[b];
            d1_lds[tid] = (1.0f / 64.0f) / (S2 + 1e-8f);
        }
        __syncthreads();
    }

    // argmax_e of d1[e]*c[e]*d0 (first max wins, like jnp.argmax)
    float best = -1.0f; int bi = 0;
#pragma unroll
    for (int e4 = 0; e4 < 16; e4++) {
        float4 dv = *(const float4*)(&d1_lds[e4 * 4]);
        float vv0 = (dv.x * c[e4 * 4 + 0]) * d0;
        float vv1 = (dv.y * c[e4 * 4 + 1]) * d0;
        float vv2 = (dv.z * c[e4 * 4 + 2]) * d0;
        float vv3 = (dv.w * c[e4 * 4 + 3]) * d0;
        if (vv0 > best) { best = vv0; bi = e4 * 4 + 0; }
        if (vv1 > best) { best = vv1; bi = e4 * 4 + 1; }
        if (vv2 > best) { best = vv2; bi = e4 * 4 + 2; }
        if (vv3 > best) { best = vv3; bi = e4 * 4 + 3; }
    }
    idx[t] = (float)bi;
}

extern "C" void kernel_launch(void* const* d_in, const int* in_sizes, int n_in,
                              void* d_out, int out_size, void* d_ws, size_t ws_size,
                              hipStream_t stream)
{
    (void)in_sizes; (void)n_in; (void)out_size; (void)ws_size;
    const float* hs = (const float*)d_in[0];   // 8192 x 2048 f32
    const float* W  = (const float*)d_in[1];   // 64 x 2048 f32
    float* out      = (float*)d_out;           // [logits | affinities | idx]

    bf16_t* wsw = (bf16_t*)d_ws;               // 512 KB prepped W (hi|lo)
    float*  sd  = (float*)d_ws + 131072;       // 480 KB sink partial slots
    float*  fl  = sd + NITER * SINK_BLOCKS * 64;   // 240 KB padded flags

    prep_whl<<<128, 256, 0, stream>>>(W, wsw);
    gemm_splitk<<<512, 256, 0, stream>>>(hs, wsw, out);   // split-K halves -> out
    sinkhorn_v8<<<SINK_BLOCKS, SINK_THREADS, 0, stream>>>(out, sd, fl);
}

// Round 10
// 213.695 us; speedup vs baseline: 1.0686x; 1.0114x over previous
//
#include <hip/hip_runtime.h>
#include <math.h>

#define T_TOKENS 8192
#define NEXP 64
#define HID 2048
#define NITER 30
#define SINK_BLOCKS 32
#define WREG 131072          // bf16 elements per W region (64 x 2048)
#define FLPAD 32             // floats per flag slot (128 B, own cache line)

typedef __bf16 bf16_t;
typedef bf16_t bf16x8 __attribute__((ext_vector_type(8)));
typedef float  f32x4  __attribute__((ext_vector_type(4)));

__device__ __forceinline__ void gload_lds16(const void* g, void* l) {
    __builtin_amdgcn_global_load_lds(
        (const __attribute__((address_space(1))) unsigned int*)g,
        (__attribute__((address_space(3))) unsigned int*)l, 16, 0, 0);
}

// ---------------------------------------------------------------------------
// SESSION CEILING NOTE (R10 = revert to best-verified R2 config, 212.6 us):
//   total ~= 70 us fixed harness/graph overhead (launch-count-invariant)
//          + ~93 us sinkhorn serial allreduce (30 x ~3.1 us coherence RTTs;
//            invariant across flag / data-as-flag / 16-32-64 participants)
//          + ~15 us sinkhorn I/O (optimum at 32 blocks)
//          + ~20-25 us GEMM (warm=15 measured; A-stream floor=11; pipeline
//            depth neutral) + ~3 us prep.
// Nine structural interventions (R1-R9) bracketed every term at its floor.
// ---------------------------------------------------------------------------

// ---------------------------------------------------------------------------
// Kernel 0: W (64x2048 f32) -> hi/lo bf16, per-64k-chunk quad-XOR-swizzled,
// linear in the exact order gemm's global_load_lds consumes.
// ---------------------------------------------------------------------------
__global__ __launch_bounds__(256)
void prep_whl(const float* __restrict__ W, bf16_t* __restrict__ wsw)
{
    int gid = blockIdx.x * 256 + threadIdx.x;   // 0..32767
    int region = gid >> 14;                     // 0 = hi, 1 = lo
    int qid = gid & 16383;
    int c = qid >> 9, L = qid & 511;
    int r = L >> 3, slot = L & 7;
    int qi = slot ^ (r & 7);
    const float* src = W + (size_t)r * HID + c * 64 + qi * 8;
    float4 v0 = *(const float4*)src;
    float4 v1 = *(const float4*)(src + 4);
    float x[8] = {v0.x, v0.y, v0.z, v0.w, v1.x, v1.y, v1.z, v1.w};
    bf16x8 q;
#pragma unroll
    for (int i = 0; i < 8; i++) {
        bf16_t h = (bf16_t)x[i];
        q[i] = (region == 0) ? h : (bf16_t)(x[i] - (float)h);
    }
    *(bf16x8*)(wsw + (size_t)region * WREG + (size_t)qid * 8) = q;
}

// ---------------------------------------------------------------------------
// Kernel 1: split-K(2) MFMA GEMM — exact R2 version. Warm pass = 15 us (R4).
// ---------------------------------------------------------------------------
__global__ __launch_bounds__(256, 2)
void gemm_splitk(const float* __restrict__ A, const bf16_t* __restrict__ Wq,
                 float* __restrict__ part)
{
    __shared__ float  sA[3][32 * 64];       // 8 KB x3 (raw f32, swizzled chunks)
    __shared__ bf16_t sW[3][2][64 * 64];    // 8 KB x6 (hi/lo bf16, swizzled)

    const int tid = threadIdx.x, lane = tid & 63, wv = tid >> 6;
    const int ks   = blockIdx.x & 1;
    const int tok0 = (blockIdx.x >> 1) * 32;
    const int mgrp = wv >> 1, ngrp = wv & 1;
    const int g = lane >> 4, m = lane & 15;
    const int arow = mgrp * 16 + m;
    const int m7 = m & 7;

    f32x4 acc0 = {0.f, 0.f, 0.f, 0.f}, acc1 = {0.f, 0.f, 0.f, 0.f};

    // staging maps (2 A-instrs + 4 W-instrs per wave per chunk)
    int ap[2], acs[2];   // A: lds position block, swizzled source chunk
#pragma unroll
    for (int j = 0; j < 2; j++) {
        int p = (wv * 2 + j) * 64 + lane;          // 16B-position 0..511
        ap[j] = p;
        int r = p >> 4, slot = p & 15;
        acs[j] = slot ^ (r & 7);                   // source 16B-chunk within row
    }

#define STAGE_CHUNK(cc, dst)                                                    \
    {                                                                           \
        const int _cc = (cc);                                                   \
        const int _d  = (dst);                                                  \
        _Pragma("unroll")                                                       \
        for (int j = 0; j < 2; j++) {                                           \
            int r = ap[j] >> 4;                                                 \
            const float* src = A + (size_t)(tok0 + r) * HID + ks * 1024         \
                             + _cc * 64 + acs[j] * 4;                           \
            gload_lds16(src, &sA[_d][(wv * 2 + j) * 256]);                      \
        }                                                                       \
        const size_t chb = ((size_t)(ks * 16 + _cc) * 512) * 8;                 \
        _Pragma("unroll")                                                       \
        for (int j = 0; j < 2; j++) {                                           \
            size_t q8 = chb + (size_t)((wv * 2 + j) * 64 + lane) * 8;           \
            gload_lds16(Wq + q8,        &sW[_d][0][(wv * 2 + j) * 512]);        \
            gload_lds16(Wq + WREG + q8, &sW[_d][1][(wv * 2 + j) * 512]);        \
        }                                                                       \
    }

#define COMPUTE_CHUNK(bufi)                                                     \
    {                                                                           \
        const float*  sAc = sA[bufi];                                           \
        const bf16_t* sWh = sW[bufi][0];                                        \
        const bf16_t* sWl = sW[bufi][1];                                        \
        _Pragma("unroll")                                                       \
        for (int k32 = 0; k32 < 2; ++k32) {                                     \
            int s0 = (k32 * 8 + g * 2) ^ m7;                                    \
            float4 x0 = *(const float4*)&sAc[arow * 64 + s0 * 4];               \
            float4 x1 = *(const float4*)&sAc[arow * 64 + (s0 ^ 1) * 4];         \
            float xs[8] = {x0.x, x0.y, x0.z, x0.w, x1.x, x1.y, x1.z, x1.w};     \
            bf16x8 fAh, fAl;                                                    \
            _Pragma("unroll")                                                   \
            for (int i = 0; i < 8; i++) {                                       \
                bf16_t h = (bf16_t)xs[i];                                       \
                fAh[i] = h; fAl[i] = (bf16_t)(xs[i] - (float)h);                \
            }                                                                   \
            const int q = k32 * 4 + g;                                          \
            {                                                                   \
                int off = (ngrp * 32 + m) * 64 + (q ^ m7) * 8;                  \
                bf16x8 fWh = *(const bf16x8*)&sWh[off];                         \
                bf16x8 fWl = *(const bf16x8*)&sWl[off];                         \
                acc0 = __builtin_amdgcn_mfma_f32_16x16x32_bf16(fAh, fWh, acc0, 0, 0, 0); \
                acc0 = __builtin_amdgcn_mfma_f32_16x16x32_bf16(fAh, fWl, acc0, 0, 0, 0); \
                acc0 = __builtin_amdgcn_mfma_f32_16x16x32_bf16(fAl, fWh, acc0, 0, 0, 0); \
            }                                                                   \
            {                                                                   \
                int off = (ngrp * 32 + 16 + m) * 64 + (q ^ m7) * 8;             \
                bf16x8 fWh = *(const bf16x8*)&sWh[off];                         \
                bf16x8 fWl = *(const bf16x8*)&sWl[off];                         \
                acc1 = __builtin_amdgcn_mfma_f32_16x16x32_bf16(fAh, fWh, acc1, 0, 0, 0); \
                acc1 = __builtin_amdgcn_mfma_f32_16x16x32_bf16(fAh, fWl, acc1, 0, 0, 0); \
                acc1 = __builtin_amdgcn_mfma_f32_16x16x32_bf16(fAl, fWh, acc1, 0, 0, 0); \
            }                                                                   \
        }                                                                       \
    }

    // prologue: fill pipeline 2 deep (12 loads in flight per wave)
    STAGE_CHUNK(0, 0);
    STAGE_CHUNK(1, 1);

    for (int cc = 0; cc < 14; ++cc) {
        STAGE_CHUNK(cc + 2, (cc + 2) % 3);
        asm volatile("s_waitcnt vmcnt(12)" ::: "memory");
        asm volatile("s_barrier" ::: "memory");
        COMPUTE_CHUNK(cc % 3);
        asm volatile("s_barrier" ::: "memory");
    }
    asm volatile("s_waitcnt vmcnt(6)" ::: "memory");
    asm volatile("s_barrier" ::: "memory");
    COMPUTE_CHUNK(2);                      // chunk 14 -> buffer 14%3=2
    asm volatile("s_waitcnt vmcnt(0)" ::: "memory");
    asm volatile("s_barrier" ::: "memory");
    COMPUTE_CHUNK(0);                      // chunk 15 -> buffer 15%3=0

    float* pb = part + (size_t)ks * T_TOKENS * 64;
#pragma unroll
    for (int i = 0; i < 4; i++) {
        int t = tok0 + mgrp * 16 + g * 4 + i;     // C: row=(lane>>4)*4+reg
        pb[(size_t)t * 64 + ngrp * 32 + m]      = acc0[i];   // col=lane&15
        pb[(size_t)t * 64 + ngrp * 32 + 16 + m] = acc1[i];
    }
#undef STAGE_CHUNK
#undef COMPUTE_CHUNK
}

// ---------------------------------------------------------------------------
// Kernel 2: persistent sinkhorn — exact R2 version (padded flags, 108 us;
// the measured optimum of the 16/32/64-participant sweep and of all five
// sync-scheme variants).
// ---------------------------------------------------------------------------
__global__ __launch_bounds__(256, 1)
void sinkhorn_v4(const float* __restrict__ part,
                 float* __restrict__ out,
                 float* __restrict__ sd,      // 30*32*64 partial slots
                 float* __restrict__ fl)      // 30*32 flags, FLPAD-padded
{
    __shared__ float tile[4][64 * 68];
    __shared__ float d1_lds[64];
    __shared__ float pl[4][64];
    const int tid = threadIdx.x, bid = blockIdx.x;
    const int wave = tid >> 6, lane = tid & 63;
    const int t = bid * 256 + tid;

    float* logits = out;
    float* aff    = out + (size_t)T_TOKENS * 64;
    float* idx    = out + (size_t)2 * T_TOKENS * 64;

    const float* p0 = part + (size_t)t * 64;
    const float* p1 = part + (size_t)T_TOKENS * 64 + (size_t)t * 64;

    float c[64];
#pragma unroll
    for (int e4 = 0; e4 < 16; e4++) {
        float4 a = *(const float4*)(p0 + e4 * 4);
        float4 b = *(const float4*)(p1 + e4 * 4);
        float4 v = {a.x + b.x, a.y + b.y, a.z + b.z, a.w + b.w};
        *(float4*)(logits + (size_t)t * 64 + e4 * 4) = v;
        float4 sg;
        sg.x = (v.x >= 0.f) ? 1.f / (1.f + expf(-v.x)) : expf(v.x) / (1.f + expf(v.x));
        sg.y = (v.y >= 0.f) ? 1.f / (1.f + expf(-v.y)) : expf(v.y) / (1.f + expf(v.y));
        sg.z = (v.z >= 0.f) ? 1.f / (1.f + expf(-v.z)) : expf(v.z) / (1.f + expf(v.z));
        sg.w = (v.w >= 0.f) ? 1.f / (1.f + expf(-v.w)) : expf(v.w) / (1.f + expf(v.w));
        *(float4*)(aff + (size_t)t * 64 + e4 * 4) = sg;
        c[e4 * 4 + 0] = expf(v.x);
        c[e4 * 4 + 1] = expf(v.y);
        c[e4 * 4 + 2] = expf(v.z);
        c[e4 * 4 + 3] = expf(v.w);
    }
    if (tid < 64) d1_lds[tid] = 1.0f;
    __syncthreads();

    float d0 = 0.f;
    float* tw = tile[wave];

    for (int iter = 0; iter < NITER; ++iter) {
        // phase 1: d0[t] = (1/T) / (sum_e d1[e]*c[e] + eps)
        float s = 0.f;
#pragma unroll
        for (int e4 = 0; e4 < 16; e4++) {
            float4 dv = *(const float4*)(&d1_lds[e4 * 4]);
            s = fmaf(c[e4 * 4 + 0], dv.x, s);
            s = fmaf(c[e4 * 4 + 1], dv.y, s);
            s = fmaf(c[e4 * 4 + 2], dv.z, s);
            s = fmaf(c[e4 * 4 + 3], dv.w, s);
        }
        d0 = (1.0f / 8192.0f) / (s + 1e-8f);

        // phase 2: block-local column sums via per-wave LDS transpose
#pragma unroll
        for (int e4 = 0; e4 < 16; e4++) {
            float4 v;
            v.x = c[e4 * 4 + 0] * d0; v.y = c[e4 * 4 + 1] * d0;
            v.z = c[e4 * 4 + 2] * d0; v.w = c[e4 * 4 + 3] * d0;
            *(float4*)(&tw[lane * 68 + e4 * 4]) = v;
        }
        __syncthreads();
        float colsum = 0.f;
#pragma unroll 16
        for (int j = 0; j < 64; j++) colsum += tw[j * 68 + lane];
        pl[wave][lane] = colsum;
        __syncthreads();

        // cross-block: publish partial + flag; poll flags; gather once
        if (tid < 64) {
            float S = pl[0][tid] + pl[1][tid] + pl[2][tid] + pl[3][tid];
            __hip_atomic_store(&sd[(size_t)(iter * SINK_BLOCKS + bid) * 64 + tid], S,
                               __ATOMIC_RELAXED, __HIP_MEMORY_SCOPE_AGENT);
            if (tid == 0) {
                __builtin_amdgcn_fence(__ATOMIC_RELEASE, "agent");
                __hip_atomic_store(&fl[(size_t)(iter * SINK_BLOCKS + bid) * FLPAD], 1.0f,
                                   __ATOMIC_RELAXED, __HIP_MEMORY_SCOPE_AGENT);
            }
            if (tid < SINK_BLOCKS) {
                int guard = 0;
                for (;;) {
                    float f = __hip_atomic_load(&fl[(size_t)(iter * SINK_BLOCKS + tid) * FLPAD],
                                                __ATOMIC_RELAXED, __HIP_MEMORY_SCOPE_AGENT);
                    if (f > 0.f || ++guard >= (1 << 20)) break;
                    __builtin_amdgcn_s_sleep(1);
                }
            }
            const float* base = sd + (size_t)iter * SINK_BLOCKS * 64 + tid;
            float v[SINK_BLOCKS];
#pragma unroll
            for (int b = 0; b < SINK_BLOCKS; b++)
                v[b] = __hip_atomic_load(base + b * 64, __ATOMIC_RELAXED,
                                         __HIP_MEMORY_SCOPE_AGENT);
            float S2 = 0.f;
#pragma unroll
            for (int b = 0; b < SINK_BLOCKS; b++) S2 += v[b];
            d1_lds[tid] = (1.0f / 64.0f) / (S2 + 1e-8f);
        }
        __syncthreads();
    }

    // argmax_e of d1[e]*c[e]*d0 (first max wins, like jnp.argmax)
    float best = -1.0f; int bi = 0;
#pragma unroll
    for (int e4 = 0; e4 < 16; e4++) {
        float4 dv = *(const float4*)(&d1_lds[e4 * 4]);
        float vv0 = (dv.x * c[e4 * 4 + 0]) * d0;
        float vv1 = (dv.y * c[e4 * 4 + 1]) * d0;
        float vv2 = (dv.z * c[e4 * 4 + 2]) * d0;
        float vv3 = (dv.w * c[e4 * 4 + 3]) * d0;
        if (vv0 > best) { best = vv0; bi = e4 * 4 + 0; }
        if (vv1 > best) { best = vv1; bi = e4 * 4 + 1; }
        if (vv2 > best) { best = vv2; bi = e4 * 4 + 2; }
        if (vv3 > best) { best = vv3; bi = e4 * 4 + 3; }
    }
    idx[t] = (float)bi;
}

extern "C" void kernel_launch(void* const* d_in, const int* in_sizes, int n_in,
                              void* d_out, int out_size, void* d_ws, size_t ws_size,
                              hipStream_t stream)
{
    (void)in_sizes; (void)n_in; (void)out_size; (void)ws_size;
    const float* hs = (const float*)d_in[0];   // 8192 x 2048 f32
    const float* W  = (const float*)d_in[1];   // 64 x 2048 f32
    float* out      = (float*)d_out;           // [logits | affinities | idx]

    bf16_t* wsw = (bf16_t*)d_ws;               // 512 KB prepped W (hi|lo)
    float*  part = (float*)d_ws + 131072;      // 4 MB: part[2][8192][64]
    float*  sd   = part + 2 * T_TOKENS * 64;   // 240 KB sink partial slots
    float*  fl   = sd + NITER * SINK_BLOCKS * 64;  // padded flags (120 KB)

    prep_whl<<<128, 256, 0, stream>>>(W, wsw);
    gemm_splitk<<<512, 256, 0, stream>>>(hs, wsw, part);
    sinkhorn_v4<<<SINK_BLOCKS, 256, 0, stream>>>(part, out, sd, fl);
}